// Round 1
// baseline (1242.774 us; speedup 1.0000x reference)
//
#include <hip/hip_runtime.h>
#include <cstddef>

#define BB 2048
#define LL 96
#define PP 96
#define NN 64

__device__ __forceinline__ float siluf(float x) {
  return x * __builtin_amdgcn_rcpf(1.0f + __expf(-x));
}
__device__ __forceinline__ float tanhf_fast(float x) {
  return 1.0f - 2.0f * __builtin_amdgcn_rcpf(1.0f + __expf(2.0f * x));
}

// ---------------- K1: x_proj over all B*L tokens + x_rec copy ----------------
__global__ __launch_bounds__(256) void k_xproj(
    const float* __restrict__ x,
    const float* __restrict__ w0, const float* __restrict__ b0,
    const float* __restrict__ w1, const float* __restrict__ b1,
    const float* __restrict__ w2, const float* __restrict__ b2,
    const float* __restrict__ w3, const float* __restrict__ b3,
    const float* __restrict__ w4, const float* __restrict__ b4,
    float* __restrict__ x_old, float* __restrict__ out)
{
  size_t tok = (size_t)blockIdx.x * 256 + threadIdx.x;  // < 196608
  const float* xp = x + tok * 8;
  float4 xa = *(const float4*)xp;
  float4 xb = *(const float4*)(xp + 4);
  *(float4*)(out + tok * 8) = xa;       // x_rec = x
  *(float4*)(out + tok * 8 + 4) = xb;
  float xin[8] = {xa.x, xa.y, xa.z, xa.w, xb.x, xb.y, xb.z, xb.w};
  float h[64];
  #pragma unroll
  for (int o = 0; o < 64; ++o) {
    float acc = b0[o];
    #pragma unroll
    for (int i = 0; i < 8; ++i) acc += w0[o * 8 + i] * xin[i];
    h[o] = siluf(acc);
  }
  #pragma unroll 1
  for (int layer = 0; layer < 3; ++layer) {
    const float* W  = (layer == 0) ? w1 : (layer == 1) ? w2 : w3;
    const float* Bv = (layer == 0) ? b1 : (layer == 1) ? b2 : b3;
    float h2[64];
    #pragma unroll
    for (int o = 0; o < 64; ++o) {
      float acc = Bv[o];
      #pragma unroll
      for (int k = 0; k < 64; ++k) acc += W[o * 64 + k] * h[k];
      h2[o] = acc;
    }
    #pragma unroll
    for (int o = 0; o < 64; ++o) h[o] = siluf(h2[o]);
  }
  float* xo = x_old + tok * 64;
  #pragma unroll
  for (int o4 = 0; o4 < 64; o4 += 4) {
    float r[4];
    #pragma unroll
    for (int u = 0; u < 4; ++u) {
      int o = o4 + u;
      float acc = b4[o];
      #pragma unroll
      for (int k = 0; k < 64; ++k) acc += w4[o * 64 + k] * h[k];
      r[u] = acc;
    }
    *(float4*)(xo + o4) = make_float4(r[0], r[1], r[2], r[3]);
  }
}

// ------- K2: per-batch dilated depthwise conv + compression + v + z0 --------
__global__ __launch_bounds__(256) void k_hist(
    const float* __restrict__ x_old,
    const float* __restrict__ conv_w, const float* __restrict__ conv_b,
    const float* __restrict__ comp_w, const float* __restrict__ comp_b,
    const float* __restrict__ xw0, const float* __restrict__ xb0,
    const float* __restrict__ xw1, const float* __restrict__ xb1,
    float* __restrict__ a0_o, float* __restrict__ v_o, float* __restrict__ z0_o)
{
  __shared__ float xo[LL * NN];   // 6144 floats
  __shared__ float red[32];
  __shared__ float hbuf[64];
  int b = blockIdx.x, tid = threadIdx.x;
  const float* src = x_old + (size_t)b * (LL * NN);
  #pragma unroll
  for (int i = 0; i < 6; ++i) {
    int e = (i * 256 + tid) * 4;
    *(float4*)(xo + e) = *(const float4*)(src + e);
  }
  __syncthreads();
  int c = tid & 63;
  float cw0 = conv_w[c * 3], cw1 = conv_w[c * 3 + 1], cw2 = conv_w[c * 3 + 2];
  float cb = conv_b[c];
  float acc[8];
  #pragma unroll
  for (int q = 0; q < 8; ++q) acc[q] = 0.f;
  #pragma unroll 1
  for (int j = 0; j < 24; ++j) {
    int e = j * 256 + tid;
    int t = e >> 6;
    float s = xo[t * 64 + c] * cw0 + cb;                  // conv, dilation 2
    if (t + 2 < LL) s += xo[(t + 2) * 64 + c] * cw1;
    if (t + 4 < LL) s += xo[(t + 4) * 64 + c] * cw2;
    float hv = siluf(s);
    #pragma unroll
    for (int q = 0; q < 8; ++q) acc[q] += hv * comp_w[q * 6144 + e];
  }
  #pragma unroll
  for (int off = 32; off >= 1; off >>= 1) {
    #pragma unroll
    for (int q = 0; q < 8; ++q) acc[q] += __shfl_xor(acc[q], off, 64);
  }
  int wave = tid >> 6, lane = tid & 63;
  if (lane < 8) {
    float sel = acc[0];
    #pragma unroll
    for (int q = 1; q < 8; ++q) sel = (lane == q) ? acc[q] : sel;
    red[wave * 8 + lane] = sel;
  }
  __syncthreads();
  if (tid < 8)
    a0_o[b * 8 + tid] = red[tid] + red[8 + tid] + red[16 + tid] + red[24 + tid] + comp_b[tid];
  // ---- v = normalize(xpp_w1 @ silu(xpp_w0 @ z0 + b0) + b1), z0 = x_old[b,95]
  if (tid < 64) {
    float a2 = xb0[tid];
    #pragma unroll 8
    for (int k = 0; k < 64; ++k) a2 += xw0[tid * 64 + k] * xo[6080 + k];
    hbuf[tid] = siluf(a2);
  }
  __syncthreads();
  float vr = 0.f;
  if (tid < 64) {
    vr = xb1[tid];
    #pragma unroll 8
    for (int k = 0; k < 64; ++k) vr += xw1[tid * 64 + k] * hbuf[k];
  }
  float s2 = vr * vr;
  #pragma unroll
  for (int off = 32; off >= 1; off >>= 1) s2 += __shfl_xor(s2, off, 64);
  if (tid < 64) {
    float nrm = sqrtf(s2) + 1e-8f;
    v_o[b * 64 + tid] = vr / nrm;
    z0_o[b * 64 + tid] = xo[6080 + tid];
  }
}

// ---------------- K3: 96-step ODE scan, one wave per batch ------------------
__global__ __launch_bounds__(256) void k_scan(
    const float* __restrict__ a0_i, const float* __restrict__ v_i, const float* __restrict__ z0_i,
    const float* __restrict__ nw0, const float* __restrict__ nb0_p,
    const float* __restrict__ nw1, const float* __restrict__ nb1_p,
    const float* __restrict__ lw0, const float* __restrict__ lb0_p,
    const float* __restrict__ lw1, const float* __restrict__ lb1_p,
    const float* __restrict__ spanA, float* __restrict__ sol)
{
  int lane = threadIdx.x & 63;
  int b = blockIdx.x * 4 + (threadIdx.x >> 6);
  float dt = fminf(fmaxf(spanA[0], 1e-8f), 7.0f);
  int i8 = lane & 7;
  float w0r[8], w1r[8], g0r[8], d1r[8];
  #pragma unroll
  for (int i = 0; i < 8; ++i) w0r[i] = nw0[lane * 8 + i];   // net_w0[lane][i]
  #pragma unroll
  for (int i = 0; i < 8; ++i) w1r[i] = nw1[i * 64 + lane];  // net_w1[i][lane]
  #pragma unroll
  for (int i = 0; i < 8; ++i) g0r[i] = lw0[i8 * 8 + i];     // lo_w0[i8][i]
  #pragma unroll
  for (int i = 0; i < 8; ++i) d1r[i] = lw1[lane * 8 + i];   // lo_w1[lane][j]
  float nb0 = nb0_p[lane];
  float nb1o = nb1_p[i8];
  float lb0o = lb0_p[i8];
  float lb1 = lb1_p[lane];
  float v = v_i[b * 64 + lane];
  float z = z0_i[b * 64 + lane];
  float a_own = a0_i[b * 8 + i8];      // lane l holds a[l&7]
  float a[8];
  #pragma unroll
  for (int i = 0; i < 8; ++i) a[i] = __shfl(a_own, i, 64);
  float* solb = sol + (size_t)b * (PP * 72);
  #pragma unroll 1
  for (int p = 0; p < PP; ++p) {
    // h1 = silu(net_w0 @ a + b0), one component per lane
    float h = nb0;
    #pragma unroll
    for (int i = 0; i < 8; ++i) h += w0r[i] * a[i];
    h = siluf(h);
    // da = tanh(net_w1 @ h1 + b1): distributed reduction
    float pr[8];
    #pragma unroll
    for (int i = 0; i < 8; ++i) pr[i] = w1r[i] * h;
    #pragma unroll
    for (int off = 1; off <= 4; off <<= 1) {
      #pragma unroll
      for (int i = 0; i < 8; ++i) pr[i] += __shfl_xor(pr[i], off, 64);
    }
    float ps = pr[0];
    #pragma unroll
    for (int i = 1; i < 8; ++i) ps = (i8 == i) ? pr[i] : ps;
    ps += __shfl_xor(ps, 8, 64);
    ps += __shfl_xor(ps, 16, 64);
    ps += __shfl_xor(ps, 32, 64);
    float da_own = tanhf_fast(ps + nb1o);
    // d = lo_w1 @ silu(lo_w0 @ a + b0) + b1
    float ga = lb0o;
    #pragma unroll
    for (int i = 0; i < 8; ++i) ga += g0r[i] * a[i];
    float g_own = siluf(ga);
    float d = lb1;
    #pragma unroll
    for (int j = 0; j < 8; ++j) d += d1r[j] * __shfl(g_own, j, 64);
    // Hz = z - 2 v (v.z);  dz = u - 2 v (v.u), u = d*Hz
    float t1 = v * z;
    #pragma unroll
    for (int off = 32; off >= 1; off >>= 1) t1 += __shfl_xor(t1, off, 64);
    float Hz = z - 2.0f * t1 * v;
    float u = d * Hz;
    float t2 = v * u;
    #pragma unroll
    for (int off = 32; off >= 1; off >>= 1) t2 += __shfl_xor(t2, off, 64);
    float dz = u - 2.0f * t2 * v;
    a_own += dt * da_own;
    z += dt * dz;
    #pragma unroll
    for (int i = 0; i < 8; ++i) a[i] = __shfl(a_own, i, 64);
    float* sp = solb + p * 72;
    if (lane < 8) sp[lane] = a_own;    // a trajectory
    sp[8 + lane] = z;                  // z trajectory
  }
}

// --------- K4: post nets per (b,p): lc head + y_hat einsum + lz head --------
__global__ __launch_bounds__(256) void k_post(
    const float* __restrict__ sol,
    const float* __restrict__ cw0, const float* __restrict__ cb0,
    const float* __restrict__ cw1, const float* __restrict__ cb1,
    const float* __restrict__ zw0, const float* __restrict__ zb0,
    const float* __restrict__ zw1, const float* __restrict__ zb1,
    float* __restrict__ out)
{
  size_t idx = (size_t)blockIdx.x * 256 + threadIdx.x;  // b*96+p, < 196608
  const float* sp = sol + idx * 72;
  float a[8];
  #pragma unroll
  for (int i = 0; i < 8; ++i) a[i] = sp[i];
  float z[64];
  #pragma unroll
  for (int n = 0; n < 64; n += 4) {
    float4 t = *(const float4*)(sp + 8 + n);
    z[n] = t.x; z[n + 1] = t.y; z[n + 2] = t.z; z[n + 3] = t.w;
  }
  float g2[8];
  #pragma unroll
  for (int j = 0; j < 8; ++j) {
    float t = cb0[j];
    #pragma unroll
    for (int i = 0; i < 8; ++i) t += cw0[j * 8 + i] * a[i];
    g2[j] = siluf(t);
  }
  // y_c = sum_n C[c][n] * z[n],  C[c][n] = lc_w1[c*64+n] @ g2 + lc_b1
  float yc[8];
  #pragma unroll
  for (int c = 0; c < 8; ++c) {
    float y = 0.f;
    #pragma unroll
    for (int n = 0; n < 64; ++n) {
      float C = cb1[c * 64 + n];
      #pragma unroll
      for (int j = 0; j < 8; ++j) C += cw1[(c * 64 + n) * 8 + j] * g2[j];
      y += C * z[n];
    }
    yc[c] = y;
  }
  // added_z = lz_w1 @ silu(lz_w0 @ z + b0) + b1
  float add[8];
  #pragma unroll
  for (int c2 = 0; c2 < 8; ++c2) add[c2] = zb1[c2];
  #pragma unroll 4
  for (int m = 0; m < 64; ++m) {
    float t = zb0[m];
    #pragma unroll
    for (int n = 0; n < 64; ++n) t += zw0[m * 64 + n] * z[n];
    float e = siluf(t);
    #pragma unroll
    for (int c3 = 0; c3 < 8; ++c3) add[c3] += zw1[c3 * 64 + m] * e;
  }
  float* op = out + (size_t)(BB * LL * 8) + idx * 8;
  *(float4*)op = make_float4(yc[0] + add[0], yc[1] + add[1], yc[2] + add[2], yc[3] + add[3]);
  *(float4*)(op + 4) = make_float4(yc[4] + add[4], yc[5] + add[5], yc[6] + add[6], yc[7] + add[7]);
}

extern "C" void kernel_launch(void* const* d_in, const int* in_sizes, int n_in,
                              void* d_out, int out_size, void* d_ws, size_t ws_size,
                              hipStream_t stream) {
  const float* x      = (const float*)d_in[0];
  const float* xp_w0  = (const float*)d_in[1];
  const float* xp_b0  = (const float*)d_in[2];
  const float* xp_w1  = (const float*)d_in[3];
  const float* xp_b1  = (const float*)d_in[4];
  const float* xp_w2  = (const float*)d_in[5];
  const float* xp_b2  = (const float*)d_in[6];
  const float* xp_w3  = (const float*)d_in[7];
  const float* xp_b3  = (const float*)d_in[8];
  const float* xp_w4  = (const float*)d_in[9];
  const float* xp_b4  = (const float*)d_in[10];
  const float* xpp_w0 = (const float*)d_in[11];
  const float* xpp_b0 = (const float*)d_in[12];
  const float* xpp_w1 = (const float*)d_in[13];
  const float* xpp_b1 = (const float*)d_in[14];
  const float* conv_w = (const float*)d_in[15];
  const float* conv_b = (const float*)d_in[16];
  const float* span_A = (const float*)d_in[17];
  const float* comp_w = (const float*)d_in[18];
  const float* comp_b = (const float*)d_in[19];
  const float* net_w0 = (const float*)d_in[20];
  const float* net_b0 = (const float*)d_in[21];
  const float* net_w1 = (const float*)d_in[22];
  const float* net_b1 = (const float*)d_in[23];
  const float* lo_w0  = (const float*)d_in[24];
  const float* lo_b0  = (const float*)d_in[25];
  const float* lo_w1  = (const float*)d_in[26];
  const float* lo_b1  = (const float*)d_in[27];
  const float* lc_w0  = (const float*)d_in[28];
  const float* lc_b0  = (const float*)d_in[29];
  const float* lc_w1  = (const float*)d_in[30];
  const float* lc_b1  = (const float*)d_in[31];
  const float* lz_w0  = (const float*)d_in[32];
  const float* lz_b0  = (const float*)d_in[33];
  const float* lz_w1  = (const float*)d_in[34];
  const float* lz_b1  = (const float*)d_in[35];

  float* ws    = (float*)d_ws;
  float* x_old = ws;                    // (B,L,64)  12582912 floats
  float* sol   = ws;                    // (B,P,72)  14155776 floats — reuses x_old region (dead after k_hist)
  float* a0    = ws + 14155776;         // (B,8)
  float* vv    = a0 + 2048 * 8;         // (B,64)
  float* z0    = vv + 2048 * 64;        // (B,64)   total ws use ≈ 57.7 MB
  float* out   = (float*)d_out;

  hipLaunchKernelGGL(k_xproj, dim3(768), dim3(256), 0, stream,
                     x, xp_w0, xp_b0, xp_w1, xp_b1, xp_w2, xp_b2, xp_w3, xp_b3,
                     xp_w4, xp_b4, x_old, out);
  hipLaunchKernelGGL(k_hist, dim3(2048), dim3(256), 0, stream,
                     x_old, conv_w, conv_b, comp_w, comp_b,
                     xpp_w0, xpp_b0, xpp_w1, xpp_b1, a0, vv, z0);
  hipLaunchKernelGGL(k_scan, dim3(512), dim3(256), 0, stream,
                     a0, vv, z0, net_w0, net_b0, net_w1, net_b1,
                     lo_w0, lo_b0, lo_w1, lo_b1, span_A, sol);
  hipLaunchKernelGGL(k_post, dim3(768), dim3(256), 0, stream,
                     sol, lc_w0, lc_b0, lc_w1, lc_b1,
                     lz_w0, lz_b0, lz_w1, lz_b1, out);
}

// Round 2
// 795.403 us; speedup vs baseline: 1.5624x; 1.5624x over previous
//
#include <hip/hip_runtime.h>
#include <cstddef>

#define BB 2048
#define LL 96
#define PP 96
#define NN 64

__device__ __forceinline__ float siluf(float x) {
  return x * __builtin_amdgcn_rcpf(1.0f + __expf(-x));
}
__device__ __forceinline__ float tanhf_fast(float x) {
  return 1.0f - 2.0f * __builtin_amdgcn_rcpf(1.0f + __expf(2.0f * x));
}

// ---------------- K1: x_proj over all B*L tokens + x_rec copy ----------------
// LDS-weight-stationary: one 16KB buffer restaged per layer; h ping-pongs in
// registers. Weight reads are wave-uniform broadcast ds_read_b128 (no
// conflicts); 4 FMAs per DS read keeps the kernel VALU-bound.
__global__ __launch_bounds__(256, 2) void k_xproj(
    const float* __restrict__ x,
    const float* __restrict__ w0, const float* __restrict__ b0,
    const float* __restrict__ w1, const float* __restrict__ b1,
    const float* __restrict__ w2, const float* __restrict__ b2,
    const float* __restrict__ w3, const float* __restrict__ b3,
    const float* __restrict__ w4, const float* __restrict__ b4,
    float* __restrict__ x_old, float* __restrict__ out)
{
  __shared__ float wbuf[4096];   // current 64x64 layer weights
  __shared__ float w0s[512];     // (64,8) first layer
  __shared__ float bs[320];      // b0..b4, 64 each
  int tid = threadIdx.x;

  *(float2*)(w0s + tid * 2) = *(const float2*)(w0 + tid * 2);
  if (tid < 64) {
    bs[tid]        = b0[tid];
    bs[64 + tid]   = b1[tid];
    bs[128 + tid]  = b2[tid];
    bs[192 + tid]  = b3[tid];
    bs[256 + tid]  = b4[tid];
  }
  #pragma unroll
  for (int i = 0; i < 4; ++i)
    ((float4*)wbuf)[i * 256 + tid] = ((const float4*)w1)[i * 256 + tid];
  __syncthreads();

  size_t tok = (size_t)blockIdx.x * 256 + tid;  // < 196608
  const float* xp = x + tok * 8;
  float4 xa = *(const float4*)xp;
  float4 xb = *(const float4*)(xp + 4);
  *(float4*)(out + tok * 8) = xa;       // x_rec = x
  *(float4*)(out + tok * 8 + 4) = xb;
  float xin[8] = {xa.x, xa.y, xa.z, xa.w, xb.x, xb.y, xb.z, xb.w};

  float h[64], h2[64];
  // layer 0: (64,8)
  #pragma unroll 8
  for (int o = 0; o < 64; ++o) {
    float acc = bs[o];
    float4 wva = *(const float4*)(w0s + o * 8);
    float4 wvb = *(const float4*)(w0s + o * 8 + 4);
    acc += wva.x * xin[0] + wva.y * xin[1] + wva.z * xin[2] + wva.w * xin[3];
    acc += wvb.x * xin[4] + wvb.y * xin[5] + wvb.z * xin[6] + wvb.w * xin[7];
    h[o] = siluf(acc);
  }

#define LAYER64(SRC, DST, BOFF)                                            \
  {                                                                        \
    _Pragma("unroll 8")                                                    \
    for (int o = 0; o < 64; ++o) {                                         \
      float acc = bs[(BOFF) + o];                                          \
      _Pragma("unroll")                                                    \
      for (int k4 = 0; k4 < 16; ++k4) {                                    \
        float4 wv = *(const float4*)(wbuf + o * 64 + k4 * 4);              \
        acc += wv.x * SRC[k4 * 4] + wv.y * SRC[k4 * 4 + 1] +               \
               wv.z * SRC[k4 * 4 + 2] + wv.w * SRC[k4 * 4 + 3];            \
      }                                                                    \
      DST[o] = siluf(acc);                                                 \
    }                                                                      \
  }

  // layer 1 (w1 already staged): h -> h2
  LAYER64(h, h2, 64)
  __syncthreads();
  #pragma unroll
  for (int i = 0; i < 4; ++i)
    ((float4*)wbuf)[i * 256 + tid] = ((const float4*)w2)[i * 256 + tid];
  __syncthreads();
  // layer 2: h2 -> h
  LAYER64(h2, h, 128)
  __syncthreads();
  #pragma unroll
  for (int i = 0; i < 4; ++i)
    ((float4*)wbuf)[i * 256 + tid] = ((const float4*)w3)[i * 256 + tid];
  __syncthreads();
  // layer 3: h -> h2
  LAYER64(h, h2, 192)
  __syncthreads();
  #pragma unroll
  for (int i = 0; i < 4; ++i)
    ((float4*)wbuf)[i * 256 + tid] = ((const float4*)w4)[i * 256 + tid];
  __syncthreads();

  // layer 4 (linear) -> x_old
  float* xo = x_old + tok * 64;
  #pragma unroll 4
  for (int o4 = 0; o4 < 64; o4 += 4) {
    float r[4];
    #pragma unroll
    for (int u = 0; u < 4; ++u) {
      int o = o4 + u;
      float acc = bs[256 + o];
      #pragma unroll
      for (int k4 = 0; k4 < 16; ++k4) {
        float4 wv = *(const float4*)(wbuf + o * 64 + k4 * 4);
        acc += wv.x * h2[k4 * 4] + wv.y * h2[k4 * 4 + 1] +
               wv.z * h2[k4 * 4 + 2] + wv.w * h2[k4 * 4 + 3];
      }
      r[u] = acc;
    }
    *(float4*)(xo + o4) = make_float4(r[0], r[1], r[2], r[3]);
  }
#undef LAYER64
}

// ------- K2: per-batch dilated depthwise conv + compression + v + z0 --------
__global__ __launch_bounds__(256) void k_hist(
    const float* __restrict__ x_old,
    const float* __restrict__ conv_w, const float* __restrict__ conv_b,
    const float* __restrict__ comp_w, const float* __restrict__ comp_b,
    const float* __restrict__ xw0, const float* __restrict__ xb0,
    const float* __restrict__ xw1, const float* __restrict__ xb1,
    float* __restrict__ a0_o, float* __restrict__ v_o, float* __restrict__ z0_o)
{
  __shared__ float xo[LL * NN];   // 6144 floats
  __shared__ float red[32];
  __shared__ float hbuf[64];
  int b = blockIdx.x, tid = threadIdx.x;
  const float* src = x_old + (size_t)b * (LL * NN);
  #pragma unroll
  for (int i = 0; i < 6; ++i) {
    int e = (i * 256 + tid) * 4;
    *(float4*)(xo + e) = *(const float4*)(src + e);
  }
  __syncthreads();
  int c = tid & 63;
  float cw0 = conv_w[c * 3], cw1 = conv_w[c * 3 + 1], cw2 = conv_w[c * 3 + 2];
  float cb = conv_b[c];
  float acc[8];
  #pragma unroll
  for (int q = 0; q < 8; ++q) acc[q] = 0.f;
  #pragma unroll 1
  for (int j = 0; j < 24; ++j) {
    int e = j * 256 + tid;
    int t = e >> 6;
    float s = xo[t * 64 + c] * cw0 + cb;                  // conv, dilation 2
    if (t + 2 < LL) s += xo[(t + 2) * 64 + c] * cw1;
    if (t + 4 < LL) s += xo[(t + 4) * 64 + c] * cw2;
    float hv = siluf(s);
    #pragma unroll
    for (int q = 0; q < 8; ++q) acc[q] += hv * comp_w[q * 6144 + e];
  }
  #pragma unroll
  for (int off = 32; off >= 1; off >>= 1) {
    #pragma unroll
    for (int q = 0; q < 8; ++q) acc[q] += __shfl_xor(acc[q], off, 64);
  }
  int wave = tid >> 6, lane = tid & 63;
  if (lane < 8) {
    float sel = acc[0];
    #pragma unroll
    for (int q = 1; q < 8; ++q) sel = (lane == q) ? acc[q] : sel;
    red[wave * 8 + lane] = sel;
  }
  __syncthreads();
  if (tid < 8)
    a0_o[b * 8 + tid] = red[tid] + red[8 + tid] + red[16 + tid] + red[24 + tid] + comp_b[tid];
  // ---- v = normalize(xpp_w1 @ silu(xpp_w0 @ z0 + b0) + b1), z0 = x_old[b,95]
  if (tid < 64) {
    float a2 = xb0[tid];
    #pragma unroll 8
    for (int k = 0; k < 64; ++k) a2 += xw0[tid * 64 + k] * xo[6080 + k];
    hbuf[tid] = siluf(a2);
  }
  __syncthreads();
  float vr = 0.f;
  if (tid < 64) {
    vr = xb1[tid];
    #pragma unroll 8
    for (int k = 0; k < 64; ++k) vr += xw1[tid * 64 + k] * hbuf[k];
  }
  float s2 = vr * vr;
  #pragma unroll
  for (int off = 32; off >= 1; off >>= 1) s2 += __shfl_xor(s2, off, 64);
  if (tid < 64) {
    float nrm = sqrtf(s2) + 1e-8f;
    v_o[b * 64 + tid] = vr / nrm;
    z0_o[b * 64 + tid] = xo[6080 + tid];
  }
}

// ---------------- K3: 96-step ODE scan, one wave per batch ------------------
__global__ __launch_bounds__(256) void k_scan(
    const float* __restrict__ a0_i, const float* __restrict__ v_i, const float* __restrict__ z0_i,
    const float* __restrict__ nw0, const float* __restrict__ nb0_p,
    const float* __restrict__ nw1, const float* __restrict__ nb1_p,
    const float* __restrict__ lw0, const float* __restrict__ lb0_p,
    const float* __restrict__ lw1, const float* __restrict__ lb1_p,
    const float* __restrict__ spanA, float* __restrict__ sol)
{
  int lane = threadIdx.x & 63;
  int b = blockIdx.x * 4 + (threadIdx.x >> 6);
  float dt = fminf(fmaxf(spanA[0], 1e-8f), 7.0f);
  int i8 = lane & 7;
  float w0r[8], w1r[8], g0r[8], d1r[8];
  #pragma unroll
  for (int i = 0; i < 8; ++i) w0r[i] = nw0[lane * 8 + i];   // net_w0[lane][i]
  #pragma unroll
  for (int i = 0; i < 8; ++i) w1r[i] = nw1[i * 64 + lane];  // net_w1[i][lane]
  #pragma unroll
  for (int i = 0; i < 8; ++i) g0r[i] = lw0[i8 * 8 + i];     // lo_w0[i8][i]
  #pragma unroll
  for (int i = 0; i < 8; ++i) d1r[i] = lw1[lane * 8 + i];   // lo_w1[lane][j]
  float nb0 = nb0_p[lane];
  float nb1o = nb1_p[i8];
  float lb0o = lb0_p[i8];
  float lb1 = lb1_p[lane];
  float v = v_i[b * 64 + lane];
  float z = z0_i[b * 64 + lane];
  float a_own = a0_i[b * 8 + i8];      // lane l holds a[l&7]
  float a[8];
  #pragma unroll
  for (int i = 0; i < 8; ++i) a[i] = __shfl(a_own, i, 64);
  float* solb = sol + (size_t)b * (PP * 72);
  #pragma unroll 1
  for (int p = 0; p < PP; ++p) {
    // h1 = silu(net_w0 @ a + b0), one component per lane
    float h = nb0;
    #pragma unroll
    for (int i = 0; i < 8; ++i) h += w0r[i] * a[i];
    h = siluf(h);
    // da = tanh(net_w1 @ h1 + b1): distributed reduction
    float pr[8];
    #pragma unroll
    for (int i = 0; i < 8; ++i) pr[i] = w1r[i] * h;
    #pragma unroll
    for (int off = 1; off <= 4; off <<= 1) {
      #pragma unroll
      for (int i = 0; i < 8; ++i) pr[i] += __shfl_xor(pr[i], off, 64);
    }
    float ps = pr[0];
    #pragma unroll
    for (int i = 1; i < 8; ++i) ps = (i8 == i) ? pr[i] : ps;
    ps += __shfl_xor(ps, 8, 64);
    ps += __shfl_xor(ps, 16, 64);
    ps += __shfl_xor(ps, 32, 64);
    float da_own = tanhf_fast(ps + nb1o);
    // d = lo_w1 @ silu(lo_w0 @ a + b0) + b1
    float ga = lb0o;
    #pragma unroll
    for (int i = 0; i < 8; ++i) ga += g0r[i] * a[i];
    float g_own = siluf(ga);
    float d = lb1;
    #pragma unroll
    for (int j = 0; j < 8; ++j) d += d1r[j] * __shfl(g_own, j, 64);
    // Hz = z - 2 v (v.z);  dz = u - 2 v (v.u), u = d*Hz
    float t1 = v * z;
    #pragma unroll
    for (int off = 32; off >= 1; off >>= 1) t1 += __shfl_xor(t1, off, 64);
    float Hz = z - 2.0f * t1 * v;
    float u = d * Hz;
    float t2 = v * u;
    #pragma unroll
    for (int off = 32; off >= 1; off >>= 1) t2 += __shfl_xor(t2, off, 64);
    float dz = u - 2.0f * t2 * v;
    a_own += dt * da_own;
    z += dt * dz;
    #pragma unroll
    for (int i = 0; i < 8; ++i) a[i] = __shfl(a_own, i, 64);
    float* sp = solb + p * 72;
    if (lane < 8) sp[lane] = a_own;    // a trajectory
    sp[8 + lane] = z;                  // z trajectory
  }
}

// --------- K4: post nets per (b,p): lc head + y_hat einsum + lz head --------
// All weights staged in LDS (broadcast ds_read_b128), VALU-bound.
__global__ __launch_bounds__(256, 2) void k_post(
    const float* __restrict__ sol,
    const float* __restrict__ cw0, const float* __restrict__ cb0,
    const float* __restrict__ cw1, const float* __restrict__ cb1,
    const float* __restrict__ zw0, const float* __restrict__ zb0,
    const float* __restrict__ zw1, const float* __restrict__ zb1,
    float* __restrict__ out)
{
  __shared__ float cw1s[4096];  // lc_w1 (512,8)
  __shared__ float zw0s[4096];  // lz_w0 (64,64)
  __shared__ float zw1s[512];   // lz_w1 (8,64)
  __shared__ float cb1s[512];   // lc_b1
  __shared__ float cw0s[64];    // lc_w0 (8,8)
  __shared__ float sm[144];     // cb0(8) zb0(64) zb1(8) ...
  int tid = threadIdx.x;
  #pragma unroll
  for (int i = 0; i < 4; ++i) {
    ((float4*)cw1s)[i * 256 + tid] = ((const float4*)cw1)[i * 256 + tid];
    ((float4*)zw0s)[i * 256 + tid] = ((const float4*)zw0)[i * 256 + tid];
  }
  if (tid < 128) ((float4*)zw1s)[tid] = ((const float4*)zw1)[tid];
  if (tid < 128) ((float4*)cb1s)[tid] = ((const float4*)cb1)[tid];
  if (tid < 64) cw0s[tid] = cw0[tid];
  if (tid < 8)  sm[tid] = cb0[tid];
  if (tid < 64) sm[8 + tid] = zb0[tid];
  if (tid < 8)  sm[72 + tid] = zb1[tid];
  __syncthreads();

  size_t idx = (size_t)blockIdx.x * 256 + tid;  // b*96+p, < 196608
  const float* sp = sol + idx * 72;
  float a[8];
  #pragma unroll
  for (int i = 0; i < 8; ++i) a[i] = sp[i];
  float z[64];
  #pragma unroll
  for (int n = 0; n < 64; n += 4) {
    float4 t = *(const float4*)(sp + 8 + n);
    z[n] = t.x; z[n + 1] = t.y; z[n + 2] = t.z; z[n + 3] = t.w;
  }
  float g2[8];
  #pragma unroll
  for (int j = 0; j < 8; ++j) {
    float4 wva = *(const float4*)(cw0s + j * 8);
    float4 wvb = *(const float4*)(cw0s + j * 8 + 4);
    float t = sm[j];
    t += wva.x * a[0] + wva.y * a[1] + wva.z * a[2] + wva.w * a[3];
    t += wvb.x * a[4] + wvb.y * a[5] + wvb.z * a[6] + wvb.w * a[7];
    g2[j] = siluf(t);
  }
  // y_c = sum_n C[c][n] * z[n],  C[c][n] = lc_w1[c*64+n] @ g2 + lc_b1
  float yc[8];
  #pragma unroll 2
  for (int c = 0; c < 8; ++c) {
    float y = 0.f;
    #pragma unroll 8
    for (int n = 0; n < 64; ++n) {
      const float* wp = cw1s + (c * 64 + n) * 8;
      float4 wva = *(const float4*)wp;
      float4 wvb = *(const float4*)(wp + 4);
      float C = cb1s[c * 64 + n];
      C += wva.x * g2[0] + wva.y * g2[1] + wva.z * g2[2] + wva.w * g2[3];
      C += wvb.x * g2[4] + wvb.y * g2[5] + wvb.z * g2[6] + wvb.w * g2[7];
      y += C * z[n];
    }
    yc[c] = y;
  }
  // added_z = lz_w1 @ silu(lz_w0 @ z + b0) + b1
  float add[8];
  #pragma unroll
  for (int c2 = 0; c2 < 8; ++c2) add[c2] = sm[72 + c2];
  #pragma unroll 4
  for (int m = 0; m < 64; ++m) {
    float t = sm[8 + m];
    #pragma unroll
    for (int n4 = 0; n4 < 16; ++n4) {
      float4 wv = *(const float4*)(zw0s + m * 64 + n4 * 4);
      t += wv.x * z[n4 * 4] + wv.y * z[n4 * 4 + 1] +
           wv.z * z[n4 * 4 + 2] + wv.w * z[n4 * 4 + 3];
    }
    float e = siluf(t);
    #pragma unroll
    for (int c3 = 0; c3 < 8; ++c3) add[c3] += zw1s[c3 * 64 + m] * e;
  }
  float* op = out + (size_t)(BB * LL * 8) + idx * 8;
  *(float4*)op = make_float4(yc[0] + add[0], yc[1] + add[1], yc[2] + add[2], yc[3] + add[3]);
  *(float4*)(op + 4) = make_float4(yc[4] + add[4], yc[5] + add[5], yc[6] + add[6], yc[7] + add[7]);
}

extern "C" void kernel_launch(void* const* d_in, const int* in_sizes, int n_in,
                              void* d_out, int out_size, void* d_ws, size_t ws_size,
                              hipStream_t stream) {
  const float* x      = (const float*)d_in[0];
  const float* xp_w0  = (const float*)d_in[1];
  const float* xp_b0  = (const float*)d_in[2];
  const float* xp_w1  = (const float*)d_in[3];
  const float* xp_b1  = (const float*)d_in[4];
  const float* xp_w2  = (const float*)d_in[5];
  const float* xp_b2  = (const float*)d_in[6];
  const float* xp_w3  = (const float*)d_in[7];
  const float* xp_b3  = (const float*)d_in[8];
  const float* xp_w4  = (const float*)d_in[9];
  const float* xp_b4  = (const float*)d_in[10];
  const float* xpp_w0 = (const float*)d_in[11];
  const float* xpp_b0 = (const float*)d_in[12];
  const float* xpp_w1 = (const float*)d_in[13];
  const float* xpp_b1 = (const float*)d_in[14];
  const float* conv_w = (const float*)d_in[15];
  const float* conv_b = (const float*)d_in[16];
  const float* span_A = (const float*)d_in[17];
  const float* comp_w = (const float*)d_in[18];
  const float* comp_b = (const float*)d_in[19];
  const float* net_w0 = (const float*)d_in[20];
  const float* net_b0 = (const float*)d_in[21];
  const float* net_w1 = (const float*)d_in[22];
  const float* net_b1 = (const float*)d_in[23];
  const float* lo_w0  = (const float*)d_in[24];
  const float* lo_b0  = (const float*)d_in[25];
  const float* lo_w1  = (const float*)d_in[26];
  const float* lo_b1  = (const float*)d_in[27];
  const float* lc_w0  = (const float*)d_in[28];
  const float* lc_b0  = (const float*)d_in[29];
  const float* lc_w1  = (const float*)d_in[30];
  const float* lc_b1  = (const float*)d_in[31];
  const float* lz_w0  = (const float*)d_in[32];
  const float* lz_b0  = (const float*)d_in[33];
  const float* lz_w1  = (const float*)d_in[34];
  const float* lz_b1  = (const float*)d_in[35];

  float* ws    = (float*)d_ws;
  float* x_old = ws;                    // (B,L,64)  12582912 floats
  float* sol   = ws;                    // (B,P,72)  14155776 floats — reuses x_old region (dead after k_hist)
  float* a0    = ws + 14155776;         // (B,8)
  float* vv    = a0 + 2048 * 8;         // (B,64)
  float* z0    = vv + 2048 * 64;        // (B,64)   total ws use ≈ 57.7 MB
  float* out   = (float*)d_out;

  hipLaunchKernelGGL(k_xproj, dim3(768), dim3(256), 0, stream,
                     x, xp_w0, xp_b0, xp_w1, xp_b1, xp_w2, xp_b2, xp_w3, xp_b3,
                     xp_w4, xp_b4, x_old, out);
  hipLaunchKernelGGL(k_hist, dim3(2048), dim3(256), 0, stream,
                     x_old, conv_w, conv_b, comp_w, comp_b,
                     xpp_w0, xpp_b0, xpp_w1, xpp_b1, a0, vv, z0);
  hipLaunchKernelGGL(k_scan, dim3(512), dim3(256), 0, stream,
                     a0, vv, z0, net_w0, net_b0, net_w1, net_b1,
                     lo_w0, lo_b0, lo_w1, lo_b1, span_A, sol);
  hipLaunchKernelGGL(k_post, dim3(768), dim3(256), 0, stream,
                     sol, lc_w0, lc_b0, lc_w1, lc_b1,
                     lz_w0, lz_b0, lz_w1, lz_b1, out);
}

// Round 3
// 491.342 us; speedup vs baseline: 2.5293x; 1.6188x over previous
//
#include <hip/hip_runtime.h>
#include <cstdint>
#include <cstddef>

#define BB 2048
#define LL 96
#define PP 96
#define NN 64
#define HSTRIDE 68   // u32 row stride for LDS tiles: 64 + 4 pad, 16B-aligned, 2-way-max banks

typedef __attribute__((ext_vector_type(8))) short short8;  // 8 bf16 (4 VGPRs)
typedef __attribute__((ext_vector_type(4))) float f32x4;

union U4S8 { uint4 u; short8 s; };

__device__ __forceinline__ float siluf(float x) {
  return x * __builtin_amdgcn_rcpf(1.0f + __expf(-x));
}
__device__ __forceinline__ float tanhf_fast(float x) {
  return 1.0f - 2.0f * __builtin_amdgcn_rcpf(1.0f + __expf(2.0f * x));
}

// split fp32 -> (bf16 hi | bf16 lo) packed in one u32 (hi in top 16). Exact split:
// hi = truncate-to-bf16(f); lo = truncate-to-bf16(f - hi). Combined ~16 mantissa bits.
__device__ __forceinline__ uint32_t packsplit(float f) {
  uint32_t b = __float_as_uint(f);
  uint32_t h = b & 0xFFFF0000u;
  float r = f - __uint_as_float(h);
  return h | (__float_as_uint(r) >> 16);
}
__device__ __forceinline__ void splitpack2(float f0, float f1, uint32_t& dhi, uint32_t& dlo) {
  uint32_t b0 = __float_as_uint(f0), b1 = __float_as_uint(f1);
  uint32_t h0 = b0 & 0xFFFF0000u, h1 = b1 & 0xFFFF0000u;
  float r0 = f0 - __uint_as_float(h0), r1 = f1 - __uint_as_float(h1);
  dhi = (h0 >> 16) | h1;
  dlo = (__float_as_uint(r0) >> 16) | (__float_as_uint(r1) & 0xFFFF0000u);
}
// two packed u32 (k0,k1) -> one dword of hi-frag + one dword of lo-frag
__device__ __forceinline__ void unpack2(uint32_t p0, uint32_t p1, uint32_t& dhi, uint32_t& dlo) {
  dhi = (p0 >> 16) | (p1 & 0xFFFF0000u);
  dlo = (p0 & 0xFFFFu) | (p1 << 16);
}
// read 8 packed u32 from LDS (one lane's k-slice) -> hi/lo bf16x8 fragments
__device__ __forceinline__ void readfrag(const uint32_t* p, short8& hi, short8& lo) {
  uint4 pa = *(const uint4*)p;
  uint4 pb = *(const uint4*)(p + 4);
  U4S8 h, l;
  unpack2(pa.x, pa.y, h.u.x, l.u.x);
  unpack2(pa.z, pa.w, h.u.y, l.u.y);
  unpack2(pb.x, pb.y, h.u.z, l.u.z);
  unpack2(pb.z, pb.w, h.u.w, l.u.w);
  hi = h.s; lo = l.s;
}

// ---------------- K1: x_proj via split-bf16 MFMA + x_rec copy ----------------
// Block = 256 thr (4 waves), 128 tokens/block (32/wave = 2 M-tiles of 16x16x32).
// Activations ping through a wave-private LDS region as packed (hi,lo) u32;
// weights restaged per layer (packed u32). 3-term split-bf16 MFMA ~= fp32.
__global__ __launch_bounds__(256, 2) void k_xproj(
    const float* __restrict__ x,
    const float* __restrict__ w0, const float* __restrict__ b0,
    const float* __restrict__ w1, const float* __restrict__ b1,
    const float* __restrict__ w2, const float* __restrict__ b2,
    const float* __restrict__ w3, const float* __restrict__ b3,
    const float* __restrict__ w4, const float* __restrict__ b4,
    float* __restrict__ x_old, float* __restrict__ out)
{
  __shared__ uint32_t hbuf[128 * HSTRIDE];  // activations, packed (hi|lo)
  __shared__ uint32_t wbuf[64 * HSTRIDE];   // current layer weights, packed
  __shared__ float bs[320];                 // b0..b4

  int tid = threadIdx.x;
  int wave = tid >> 6, lane = tid & 63;
  int quad = lane >> 4, m16 = lane & 15;
  size_t tokBase = (size_t)blockIdx.x * 128;

  // x_rec = x (pure copy): 128 tok * 8 = 1024 floats = 1 float4/thread
  {
    size_t e = tokBase * 8 + (size_t)tid * 4;
    *(float4*)(out + e) = *(const float4*)(x + e);
  }
  if (tid < 64) {
    bs[tid]       = b0[tid];
    bs[64 + tid]  = b1[tid];
    bs[128 + tid] = b2[tid];
    bs[192 + tid] = b3[tid];
    bs[256 + tid] = b4[tid];
  }
  __syncthreads();

  // ---- layer 0: [128x8] @ w0^T(8->64), K padded to 32 (quads 1..3 zero) ----
  short8 A0h[2], A0l[2];
  #pragma unroll
  for (int mt = 0; mt < 2; ++mt) {
    U4S8 h, l;
    h.u = make_uint4(0, 0, 0, 0); l.u = make_uint4(0, 0, 0, 0);
    if (quad == 0) {
      const float* xp = x + (tokBase + wave * 32 + mt * 16 + m16) * 8;
      float4 xa = *(const float4*)xp;
      float4 xb = *(const float4*)(xp + 4);
      splitpack2(xa.x, xa.y, h.u.x, l.u.x);
      splitpack2(xa.z, xa.w, h.u.y, l.u.y);
      splitpack2(xb.x, xb.y, h.u.z, l.u.z);
      splitpack2(xb.z, xb.w, h.u.w, l.u.w);
    }
    A0h[mt] = h.s; A0l[mt] = l.s;
  }
  short8 B0h[4], B0l[4];
  #pragma unroll
  for (int nt = 0; nt < 4; ++nt) {
    U4S8 h, l;
    h.u = make_uint4(0, 0, 0, 0); l.u = make_uint4(0, 0, 0, 0);
    if (quad == 0) {
      const float* wp = w0 + (nt * 16 + m16) * 8;
      float4 wa = *(const float4*)wp;
      float4 wb = *(const float4*)(wp + 4);
      splitpack2(wa.x, wa.y, h.u.x, l.u.x);
      splitpack2(wa.z, wa.w, h.u.y, l.u.y);
      splitpack2(wb.x, wb.y, h.u.z, l.u.z);
      splitpack2(wb.z, wb.w, h.u.w, l.u.w);
    }
    B0h[nt] = h.s; B0l[nt] = l.s;
  }
  {
    f32x4 acc[2][4];
    #pragma unroll
    for (int mt = 0; mt < 2; ++mt)
      #pragma unroll
      for (int nt = 0; nt < 4; ++nt) {
        float bv = bs[nt * 16 + m16];
        acc[mt][nt] = (f32x4){bv, bv, bv, bv};
      }
    #pragma unroll
    for (int mt = 0; mt < 2; ++mt)
      #pragma unroll
      for (int nt = 0; nt < 4; ++nt)
        acc[mt][nt] = __builtin_amdgcn_mfma_f32_16x16x32_bf16(A0h[mt], B0h[nt], acc[mt][nt], 0, 0, 0);
    #pragma unroll
    for (int mt = 0; mt < 2; ++mt)
      #pragma unroll
      for (int nt = 0; nt < 4; ++nt)
        acc[mt][nt] = __builtin_amdgcn_mfma_f32_16x16x32_bf16(A0l[mt], B0h[nt], acc[mt][nt], 0, 0, 0);
    #pragma unroll
    for (int mt = 0; mt < 2; ++mt)
      #pragma unroll
      for (int nt = 0; nt < 4; ++nt)
        acc[mt][nt] = __builtin_amdgcn_mfma_f32_16x16x32_bf16(A0h[mt], B0l[nt], acc[mt][nt], 0, 0, 0);
    // silu + pack -> hbuf (rows are wave-private)
    #pragma unroll
    for (int mt = 0; mt < 2; ++mt)
      #pragma unroll
      for (int nt = 0; nt < 4; ++nt)
        #pragma unroll
        for (int r = 0; r < 4; ++r) {
          float s = siluf(acc[mt][nt][r]);
          hbuf[(wave * 32 + mt * 16 + quad * 4 + r) * HSTRIDE + nt * 16 + m16] = packsplit(s);
        }
  }

  // ---- layers 1..4: [128x64] @ W^T(64x64) ----
  const float* Ws[4] = {w1, w2, w3, w4};
  #pragma unroll 1
  for (int lyr = 0; lyr < 4; ++lyr) {
    const float* w = Ws[lyr];
    // stage packed weights: 4096 fp32 -> packed u32, b128 LDS writes
    #pragma unroll
    for (int i = 0; i < 4; ++i) {
      int e4 = i * 256 + tid;              // float4 index
      int o = e4 >> 4, k = (e4 & 15) << 2;
      float4 wv = ((const float4*)w)[e4];
      *(uint4*)(wbuf + o * HSTRIDE + k) =
          make_uint4(packsplit(wv.x), packsplit(wv.y), packsplit(wv.z), packsplit(wv.w));
    }
    __syncthreads();  // staging visible
    short8 Bh[8], Bl[8];  // [nt*2+ks]
    #pragma unroll
    for (int nt = 0; nt < 4; ++nt)
      #pragma unroll
      for (int ks = 0; ks < 2; ++ks)
        readfrag(wbuf + (nt * 16 + m16) * HSTRIDE + ks * 32 + quad * 8, Bh[nt * 2 + ks], Bl[nt * 2 + ks]);
    short8 Ah[4], Al[4];  // [mt*2+ks]
    #pragma unroll
    for (int mt = 0; mt < 2; ++mt)
      #pragma unroll
      for (int ks = 0; ks < 2; ++ks)
        readfrag(hbuf + (wave * 32 + mt * 16 + m16) * HSTRIDE + ks * 32 + quad * 8, Ah[mt * 2 + ks], Al[mt * 2 + ks]);
    __syncthreads();  // all wbuf reads done -> next staging safe

    f32x4 acc[2][4];
    #pragma unroll
    for (int mt = 0; mt < 2; ++mt)
      #pragma unroll
      for (int nt = 0; nt < 4; ++nt) {
        float bv = bs[(lyr + 1) * 64 + nt * 16 + m16];
        acc[mt][nt] = (f32x4){bv, bv, bv, bv};
      }
    #pragma unroll
    for (int ks = 0; ks < 2; ++ks)
      #pragma unroll
      for (int mt = 0; mt < 2; ++mt)
        #pragma unroll
        for (int nt = 0; nt < 4; ++nt)
          acc[mt][nt] = __builtin_amdgcn_mfma_f32_16x16x32_bf16(Ah[mt * 2 + ks], Bh[nt * 2 + ks], acc[mt][nt], 0, 0, 0);
    #pragma unroll
    for (int ks = 0; ks < 2; ++ks)
      #pragma unroll
      for (int mt = 0; mt < 2; ++mt)
        #pragma unroll
        for (int nt = 0; nt < 4; ++nt)
          acc[mt][nt] = __builtin_amdgcn_mfma_f32_16x16x32_bf16(Al[mt * 2 + ks], Bh[nt * 2 + ks], acc[mt][nt], 0, 0, 0);
    #pragma unroll
    for (int ks = 0; ks < 2; ++ks)
      #pragma unroll
      for (int mt = 0; mt < 2; ++mt)
        #pragma unroll
        for (int nt = 0; nt < 4; ++nt)
          acc[mt][nt] = __builtin_amdgcn_mfma_f32_16x16x32_bf16(Ah[mt * 2 + ks], Bl[nt * 2 + ks], acc[mt][nt], 0, 0, 0);

    if (lyr < 3) {
      #pragma unroll
      for (int mt = 0; mt < 2; ++mt)
        #pragma unroll
        for (int nt = 0; nt < 4; ++nt)
          #pragma unroll
          for (int r = 0; r < 4; ++r) {
            float s = siluf(acc[mt][nt][r]);
            hbuf[(wave * 32 + mt * 16 + quad * 4 + r) * HSTRIDE + nt * 16 + m16] = packsplit(s);
          }
    } else {
      // final linear layer -> x_old fp32
      #pragma unroll
      for (int mt = 0; mt < 2; ++mt)
        #pragma unroll
        for (int nt = 0; nt < 4; ++nt)
          #pragma unroll
          for (int r = 0; r < 4; ++r) {
            size_t t = tokBase + wave * 32 + mt * 16 + quad * 4 + r;
            x_old[t * 64 + nt * 16 + m16] = acc[mt][nt][r];
          }
    }
  }
}

// ------- K2: per-batch dilated depthwise conv + compression + v + z0 --------
__global__ __launch_bounds__(256) void k_hist(
    const float* __restrict__ x_old,
    const float* __restrict__ conv_w, const float* __restrict__ conv_b,
    const float* __restrict__ comp_w, const float* __restrict__ comp_b,
    const float* __restrict__ xw0, const float* __restrict__ xb0,
    const float* __restrict__ xw1, const float* __restrict__ xb1,
    float* __restrict__ a0_o, float* __restrict__ v_o, float* __restrict__ z0_o)
{
  __shared__ float xo[LL * NN];   // 6144 floats
  __shared__ float red[32];
  __shared__ float hbuf[64];
  int b = blockIdx.x, tid = threadIdx.x;
  const float* src = x_old + (size_t)b * (LL * NN);
  #pragma unroll
  for (int i = 0; i < 6; ++i) {
    int e = (i * 256 + tid) * 4;
    *(float4*)(xo + e) = *(const float4*)(src + e);
  }
  __syncthreads();
  int c = tid & 63;
  float cw0 = conv_w[c * 3], cw1 = conv_w[c * 3 + 1], cw2 = conv_w[c * 3 + 2];
  float cb = conv_b[c];
  float acc[8];
  #pragma unroll
  for (int q = 0; q < 8; ++q) acc[q] = 0.f;
  #pragma unroll 1
  for (int j = 0; j < 24; ++j) {
    int e = j * 256 + tid;
    int t = e >> 6;
    float s = xo[t * 64 + c] * cw0 + cb;                  // conv, dilation 2
    if (t + 2 < LL) s += xo[(t + 2) * 64 + c] * cw1;
    if (t + 4 < LL) s += xo[(t + 4) * 64 + c] * cw2;
    float hv = siluf(s);
    #pragma unroll
    for (int q = 0; q < 8; ++q) acc[q] += hv * comp_w[q * 6144 + e];
  }
  #pragma unroll
  for (int off = 32; off >= 1; off >>= 1) {
    #pragma unroll
    for (int q = 0; q < 8; ++q) acc[q] += __shfl_xor(acc[q], off, 64);
  }
  int wave = tid >> 6, lane = tid & 63;
  if (lane < 8) {
    float sel = acc[0];
    #pragma unroll
    for (int q = 1; q < 8; ++q) sel = (lane == q) ? acc[q] : sel;
    red[wave * 8 + lane] = sel;
  }
  __syncthreads();
  if (tid < 8)
    a0_o[b * 8 + tid] = red[tid] + red[8 + tid] + red[16 + tid] + red[24 + tid] + comp_b[tid];
  // ---- v = normalize(xpp_w1 @ silu(xpp_w0 @ z0 + b0) + b1), z0 = x_old[b,95]
  if (tid < 64) {
    float a2 = xb0[tid];
    #pragma unroll 8
    for (int k = 0; k < 64; ++k) a2 += xw0[tid * 64 + k] * xo[6080 + k];
    hbuf[tid] = siluf(a2);
  }
  __syncthreads();
  float vr = 0.f;
  if (tid < 64) {
    vr = xb1[tid];
    #pragma unroll 8
    for (int k = 0; k < 64; ++k) vr += xw1[tid * 64 + k] * hbuf[k];
  }
  float s2 = vr * vr;
  #pragma unroll
  for (int off = 32; off >= 1; off >>= 1) s2 += __shfl_xor(s2, off, 64);
  if (tid < 64) {
    float nrm = sqrtf(s2) + 1e-8f;
    v_o[b * 64 + tid] = vr / nrm;
    z0_o[b * 64 + tid] = xo[6080 + tid];
  }
}

// ---------------- K3: 96-step ODE scan, one wave per batch ------------------
__global__ __launch_bounds__(256) void k_scan(
    const float* __restrict__ a0_i, const float* __restrict__ v_i, const float* __restrict__ z0_i,
    const float* __restrict__ nw0, const float* __restrict__ nb0_p,
    const float* __restrict__ nw1, const float* __restrict__ nb1_p,
    const float* __restrict__ lw0, const float* __restrict__ lb0_p,
    const float* __restrict__ lw1, const float* __restrict__ lb1_p,
    const float* __restrict__ spanA, float* __restrict__ sol)
{
  int lane = threadIdx.x & 63;
  int b = blockIdx.x * 4 + (threadIdx.x >> 6);
  float dt = fminf(fmaxf(spanA[0], 1e-8f), 7.0f);
  int i8 = lane & 7;
  float w0r[8], w1r[8], g0r[8], d1r[8];
  #pragma unroll
  for (int i = 0; i < 8; ++i) w0r[i] = nw0[lane * 8 + i];   // net_w0[lane][i]
  #pragma unroll
  for (int i = 0; i < 8; ++i) w1r[i] = nw1[i * 64 + lane];  // net_w1[i][lane]
  #pragma unroll
  for (int i = 0; i < 8; ++i) g0r[i] = lw0[i8 * 8 + i];     // lo_w0[i8][i]
  #pragma unroll
  for (int i = 0; i < 8; ++i) d1r[i] = lw1[lane * 8 + i];   // lo_w1[lane][j]
  float nb0 = nb0_p[lane];
  float nb1o = nb1_p[i8];
  float lb0o = lb0_p[i8];
  float lb1 = lb1_p[lane];
  float v = v_i[b * 64 + lane];
  float z = z0_i[b * 64 + lane];
  float a_own = a0_i[b * 8 + i8];      // lane l holds a[l&7]
  float a[8];
  #pragma unroll
  for (int i = 0; i < 8; ++i) a[i] = __shfl(a_own, i, 64);
  float* solb = sol + (size_t)b * (PP * 72);
  #pragma unroll 1
  for (int p = 0; p < PP; ++p) {
    // h1 = silu(net_w0 @ a + b0), one component per lane
    float h = nb0;
    #pragma unroll
    for (int i = 0; i < 8; ++i) h += w0r[i] * a[i];
    h = siluf(h);
    // da = tanh(net_w1 @ h1 + b1): distributed reduction
    float pr[8];
    #pragma unroll
    for (int i = 0; i < 8; ++i) pr[i] = w1r[i] * h;
    #pragma unroll
    for (int off = 1; off <= 4; off <<= 1) {
      #pragma unroll
      for (int i = 0; i < 8; ++i) pr[i] += __shfl_xor(pr[i], off, 64);
    }
    float ps = pr[0];
    #pragma unroll
    for (int i = 1; i < 8; ++i) ps = (i8 == i) ? pr[i] : ps;
    ps += __shfl_xor(ps, 8, 64);
    ps += __shfl_xor(ps, 16, 64);
    ps += __shfl_xor(ps, 32, 64);
    float da_own = tanhf_fast(ps + nb1o);
    // d = lo_w1 @ silu(lo_w0 @ a + b0) + b1
    float ga = lb0o;
    #pragma unroll
    for (int i = 0; i < 8; ++i) ga += g0r[i] * a[i];
    float g_own = siluf(ga);
    float d = lb1;
    #pragma unroll
    for (int j = 0; j < 8; ++j) d += d1r[j] * __shfl(g_own, j, 64);
    // Hz = z - 2 v (v.z);  dz = u - 2 v (v.u), u = d*Hz
    float t1 = v * z;
    #pragma unroll
    for (int off = 32; off >= 1; off >>= 1) t1 += __shfl_xor(t1, off, 64);
    float Hz = z - 2.0f * t1 * v;
    float u = d * Hz;
    float t2 = v * u;
    #pragma unroll
    for (int off = 32; off >= 1; off >>= 1) t2 += __shfl_xor(t2, off, 64);
    float dz = u - 2.0f * t2 * v;
    a_own += dt * da_own;
    z += dt * dz;
    #pragma unroll
    for (int i = 0; i < 8; ++i) a[i] = __shfl(a_own, i, 64);
    float* sp = solb + p * 72;
    if (lane < 8) sp[lane] = a_own;    // a trajectory
    sp[8 + lane] = z;                  // z trajectory
  }
}

// --------- K4: post nets per (b,p): lc head + y_hat einsum + lz head --------
__global__ __launch_bounds__(256, 2) void k_post(
    const float* __restrict__ sol,
    const float* __restrict__ cw0, const float* __restrict__ cb0,
    const float* __restrict__ cw1, const float* __restrict__ cb1,
    const float* __restrict__ zw0, const float* __restrict__ zb0,
    const float* __restrict__ zw1, const float* __restrict__ zb1,
    float* __restrict__ out)
{
  __shared__ float cw1s[4096];  // lc_w1 (512,8)
  __shared__ float zw0s[4096];  // lz_w0 (64,64)
  __shared__ float zw1s[512];   // lz_w1 (8,64)
  __shared__ float cb1s[512];   // lc_b1
  __shared__ float cw0s[64];    // lc_w0 (8,8)
  __shared__ float sm[144];     // cb0(8) zb0(64) zb1(8)
  int tid = threadIdx.x;
  #pragma unroll
  for (int i = 0; i < 4; ++i) {
    ((float4*)cw1s)[i * 256 + tid] = ((const float4*)cw1)[i * 256 + tid];
    ((float4*)zw0s)[i * 256 + tid] = ((const float4*)zw0)[i * 256 + tid];
  }
  if (tid < 128) ((float4*)zw1s)[tid] = ((const float4*)zw1)[tid];
  if (tid < 128) ((float4*)cb1s)[tid] = ((const float4*)cb1)[tid];
  if (tid < 64) cw0s[tid] = cw0[tid];
  if (tid < 8)  sm[tid] = cb0[tid];
  if (tid < 64) sm[8 + tid] = zb0[tid];
  if (tid < 8)  sm[72 + tid] = zb1[tid];
  __syncthreads();

  size_t idx = (size_t)blockIdx.x * 256 + tid;  // b*96+p, < 196608
  const float* sp = sol + idx * 72;
  float a[8];
  #pragma unroll
  for (int i = 0; i < 8; ++i) a[i] = sp[i];
  float z[64];
  #pragma unroll
  for (int n = 0; n < 64; n += 4) {
    float4 t = *(const float4*)(sp + 8 + n);
    z[n] = t.x; z[n + 1] = t.y; z[n + 2] = t.z; z[n + 3] = t.w;
  }
  float g2[8];
  #pragma unroll
  for (int j = 0; j < 8; ++j) {
    float4 wva = *(const float4*)(cw0s + j * 8);
    float4 wvb = *(const float4*)(cw0s + j * 8 + 4);
    float t = sm[j];
    t += wva.x * a[0] + wva.y * a[1] + wva.z * a[2] + wva.w * a[3];
    t += wvb.x * a[4] + wvb.y * a[5] + wvb.z * a[6] + wvb.w * a[7];
    g2[j] = siluf(t);
  }
  // y_c = sum_n C[c][n] * z[n],  C[c][n] = lc_w1[c*64+n] @ g2 + lc_b1
  float yc[8];
  #pragma unroll 2
  for (int c = 0; c < 8; ++c) {
    float y = 0.f;
    #pragma unroll 8
    for (int n = 0; n < 64; ++n) {
      const float* wp = cw1s + (c * 64 + n) * 8;
      float4 wva = *(const float4*)wp;
      float4 wvb = *(const float4*)(wp + 4);
      float C = cb1s[c * 64 + n];
      C += wva.x * g2[0] + wva.y * g2[1] + wva.z * g2[2] + wva.w * g2[3];
      C += wvb.x * g2[4] + wvb.y * g2[5] + wvb.z * g2[6] + wvb.w * g2[7];
      y += C * z[n];
    }
    yc[c] = y;
  }
  // added_z = lz_w1 @ silu(lz_w0 @ z + b0) + b1
  float add[8];
  #pragma unroll
  for (int c2 = 0; c2 < 8; ++c2) add[c2] = sm[72 + c2];
  #pragma unroll 4
  for (int m = 0; m < 64; ++m) {
    float t = sm[8 + m];
    #pragma unroll
    for (int n4 = 0; n4 < 16; ++n4) {
      float4 wv = *(const float4*)(zw0s + m * 64 + n4 * 4);
      t += wv.x * z[n4 * 4] + wv.y * z[n4 * 4 + 1] +
           wv.z * z[n4 * 4 + 2] + wv.w * z[n4 * 4 + 3];
    }
    float e = siluf(t);
    #pragma unroll
    for (int c3 = 0; c3 < 8; ++c3) add[c3] += zw1s[c3 * 64 + m] * e;
  }
  float* op = out + (size_t)(BB * LL * 8) + idx * 8;
  *(float4*)op = make_float4(yc[0] + add[0], yc[1] + add[1], yc[2] + add[2], yc[3] + add[3]);
  *(float4*)(op + 4) = make_float4(yc[4] + add[4], yc[5] + add[5], yc[6] + add[6], yc[7] + add[7]);
}

extern "C" void kernel_launch(void* const* d_in, const int* in_sizes, int n_in,
                              void* d_out, int out_size, void* d_ws, size_t ws_size,
                              hipStream_t stream) {
  const float* x      = (const float*)d_in[0];
  const float* xp_w0  = (const float*)d_in[1];
  const float* xp_b0  = (const float*)d_in[2];
  const float* xp_w1  = (const float*)d_in[3];
  const float* xp_b1  = (const float*)d_in[4];
  const float* xp_w2  = (const float*)d_in[5];
  const float* xp_b2  = (const float*)d_in[6];
  const float* xp_w3  = (const float*)d_in[7];
  const float* xp_b3  = (const float*)d_in[8];
  const float* xp_w4  = (const float*)d_in[9];
  const float* xp_b4  = (const float*)d_in[10];
  const float* xpp_w0 = (const float*)d_in[11];
  const float* xpp_b0 = (const float*)d_in[12];
  const float* xpp_w1 = (const float*)d_in[13];
  const float* xpp_b1 = (const float*)d_in[14];
  const float* conv_w = (const float*)d_in[15];
  const float* conv_b = (const float*)d_in[16];
  const float* span_A = (const float*)d_in[17];
  const float* comp_w = (const float*)d_in[18];
  const float* comp_b = (const float*)d_in[19];
  const float* net_w0 = (const float*)d_in[20];
  const float* net_b0 = (const float*)d_in[21];
  const float* net_w1 = (const float*)d_in[22];
  const float* net_b1 = (const float*)d_in[23];
  const float* lo_w0  = (const float*)d_in[24];
  const float* lo_b0  = (const float*)d_in[25];
  const float* lo_w1  = (const float*)d_in[26];
  const float* lo_b1  = (const float*)d_in[27];
  const float* lc_w0  = (const float*)d_in[28];
  const float* lc_b0  = (const float*)d_in[29];
  const float* lc_w1  = (const float*)d_in[30];
  const float* lc_b1  = (const float*)d_in[31];
  const float* lz_w0  = (const float*)d_in[32];
  const float* lz_b0  = (const float*)d_in[33];
  const float* lz_w1  = (const float*)d_in[34];
  const float* lz_b1  = (const float*)d_in[35];

  float* ws    = (float*)d_ws;
  float* x_old = ws;                    // (B,L,64)  12582912 floats
  float* sol   = ws;                    // (B,P,72)  14155776 floats — reuses x_old region (dead after k_hist)
  float* a0    = ws + 14155776;         // (B,8)
  float* vv    = a0 + 2048 * 8;         // (B,64)
  float* z0    = vv + 2048 * 64;        // (B,64)   total ws use ≈ 57.7 MB
  float* out   = (float*)d_out;

  hipLaunchKernelGGL(k_xproj, dim3(1536), dim3(256), 0, stream,
                     x, xp_w0, xp_b0, xp_w1, xp_b1, xp_w2, xp_b2, xp_w3, xp_b3,
                     xp_w4, xp_b4, x_old, out);
  hipLaunchKernelGGL(k_hist, dim3(2048), dim3(256), 0, stream,
                     x_old, conv_w, conv_b, comp_w, comp_b,
                     xpp_w0, xpp_b0, xpp_w1, xpp_b1, a0, vv, z0);
  hipLaunchKernelGGL(k_scan, dim3(512), dim3(256), 0, stream,
                     a0, vv, z0, net_w0, net_b0, net_w1, net_b1,
                     lo_w0, lo_b0, lo_w1, lo_b1, span_A, sol);
  hipLaunchKernelGGL(k_post, dim3(768), dim3(256), 0, stream,
                     sol, lc_w0, lc_b0, lc_w1, lc_b1,
                     lz_w0, lz_b0, lz_w1, lz_b1, out);
}